// Round 4
// baseline (51.032 us; speedup 1.0000x reference)
//
#include <hip/hip_runtime.h>
#include <math.h>

#define N9     6000
#define N10    9000
#define FDIM   128
#define ALPHA  0.2f
#define MAXNBR 64
#define ROWBLOCKS 2048

typedef float f32x4 __attribute__((ext_vector_type(4)));

// ---------------------------------------------------------------------------
// Fully fused GAT layer: one persistent-block kernel, grid-stride over query
// rows. Per row:
//   P0: wave 0 loads Q[i], stashes it in LDS, computes qa1 = Q[i].a1,
//       qa2 = Q[i].a2 via shuffle reduce (other waves fall through to scan).
//   P1: all 256 threads scan the adjacency row (f32x4, nontemporal) and
//       push nonzero column indices into an LDS list (avg degree ~4).
//   P2: one wave per neighbor: load K[j], stash in LDS, compute
//       ka2 = K[j].a2, e = leaky_relu(qa1 + ka2).
//   P3: thread 0: stable softmax over {self} U neighbors (self is always
//       unmasked -> denominator > 0, reference NaN path is dead).
//   P4: 128 threads: h = w_self*Q[i] + sum_c w_c*K[j_c] (all from LDS), elu.
// ---------------------------------------------------------------------------
__global__ __launch_bounds__(256)
void gat_fused_kernel(const int* __restrict__ version,
                      const float* __restrict__ U9,
                      const float* __restrict__ U10,
                      const float* __restrict__ a,
                      const float* __restrict__ adj9to10,
                      const float* __restrict__ adj10to9,
                      float* __restrict__ out) {
    const int v  = version[0];
    const int nq = v ? N10 : N9;
    const int nk = v ? N9  : N10;
    const float* __restrict__ Q      = v ? U10 : U9;
    const float* __restrict__ K      = v ? U9  : U10;
    const float* __restrict__ adjmat = v ? adj10to9 : adj9to10;

    __shared__ float s_a1[FDIM];
    __shared__ float s_a2[FDIM];
    __shared__ float s_q[FDIM];
    __shared__ float s_k[MAXNBR][FDIM];
    __shared__ int   s_j[MAXNBR];
    __shared__ float s_e[MAXNBR];
    __shared__ float s_w[MAXNBR];
    __shared__ int   s_cnt;
    __shared__ float s_qa1, s_qa2, s_wself;

    const int t    = threadIdx.x;
    const int wave = t >> 6;
    const int lane = t & 63;

    if (t < FDIM) { s_a1[t] = a[t]; s_a2[t] = a[FDIM + t]; }
    __syncthreads();

    const int n4 = nk >> 2;

    for (int i = blockIdx.x; i < nq; i += gridDim.x) {
        if (t == 0) s_cnt = 0;
        __syncthreads();  // s_cnt reset visible before scan atomics

        // P0: wave 0 computes the query-row dots and stashes Q[i].
        if (wave == 0) {
            const float* x = Q + (size_t)i * FDIM;
            float x0 = x[lane], x1 = x[lane + 64];
            s_q[lane] = x0; s_q[lane + 64] = x1;
            float s1 = x0 * s_a1[lane] + x1 * s_a1[lane + 64];
            float s2 = x0 * s_a2[lane] + x1 * s_a2[lane + 64];
            #pragma unroll
            for (int o = 32; o > 0; o >>= 1) {
                s1 += __shfl_down(s1, o);
                s2 += __shfl_down(s2, o);
            }
            if (lane == 0) { s_qa1 = s1; s_qa2 = s2; }
        }

        // P1: scan adjacency row (nontemporal — streamed exactly once).
        const f32x4* __restrict__ adj4 = (const f32x4*)(adjmat + (size_t)i * nk);
        for (int p0 = t; p0 < n4; p0 += 256 * 4) {
            const int p1 = p0 + 256, p2 = p0 + 512, p3 = p0 + 768;
            f32x4 r0 = __builtin_nontemporal_load(&adj4[p0]);
            f32x4 r1 = (f32x4)(0.f);
            f32x4 r2 = r1, r3 = r1;
            if (p1 < n4) r1 = __builtin_nontemporal_load(&adj4[p1]);
            if (p2 < n4) r2 = __builtin_nontemporal_load(&adj4[p2]);
            if (p3 < n4) r3 = __builtin_nontemporal_load(&adj4[p3]);

            f32x4 rr[4] = {r0, r1, r2, r3};
            int   pp[4] = {p0, p1, p2, p3};
            #pragma unroll
            for (int u = 0; u < 4; ++u) {
                f32x4 vv = rr[u];
                if (vv.x > 0.f || vv.y > 0.f || vv.z > 0.f || vv.w > 0.f) {
                    float va[4] = {vv.x, vv.y, vv.z, vv.w};
                    #pragma unroll
                    for (int c = 0; c < 4; ++c) {
                        if (va[c] > 0.f) {
                            int idx = atomicAdd(&s_cnt, 1);
                            if (idx < MAXNBR) s_j[idx] = pp[u] * 4 + c;
                        }
                    }
                }
            }
        }
        __syncthreads();  // cnt, s_j, s_qa1/s_qa2, s_q all final

        const int cnt = (s_cnt < MAXNBR) ? s_cnt : MAXNBR;

        // P2: one wave per neighbor — load K[j], stash, dot with a2.
        for (int c = wave; c < cnt; c += 4) {
            const int j = s_j[c];
            const float* k = K + (size_t)j * FDIM;
            float x0 = k[lane], x1 = k[lane + 64];
            s_k[c][lane] = x0; s_k[c][lane + 64] = x1;
            float s2 = x0 * s_a2[lane] + x1 * s_a2[lane + 64];
            #pragma unroll
            for (int o = 32; o > 0; o >>= 1) s2 += __shfl_down(s2, o);
            if (lane == 0) {
                float e = s_qa1 + s2;
                s_e[c] = (e >= 0.f) ? e : ALPHA * e;
            }
        }
        __syncthreads();

        // P3: small softmax.
        if (t == 0) {
            float se = s_qa1 + s_qa2;
            se = (se >= 0.f) ? se : ALPHA * se;
            float m = se;
            for (int c = 0; c < cnt; ++c) m = fmaxf(m, s_e[c]);
            float wself = expf(se - m);
            float wsum  = wself;
            for (int c = 0; c < cnt; ++c) {
                float w = expf(s_e[c] - m);
                s_w[c] = w;
                wsum += w;
            }
            float inv = 1.f / wsum;
            s_wself = wself * inv;
            for (int c = 0; c < cnt; ++c) s_w[c] *= inv;
        }
        __syncthreads();

        // P4: weighted feature accumulation + elu (all operands in LDS).
        if (t < FDIM) {
            float h = s_wself * s_q[t];
            for (int c = 0; c < cnt; ++c) h += s_w[c] * s_k[c][t];
            h = (h > 0.f) ? h : expm1f(h);
            out[(size_t)i * FDIM + t] = h;
        }
        __syncthreads();  // protect LDS reuse for next row
    }
}

extern "C" void kernel_launch(void* const* d_in, const int* in_sizes, int n_in,
                              void* d_out, int out_size, void* d_ws, size_t ws_size,
                              hipStream_t stream) {
    const int*   d_version = (const int*)d_in[0];
    const float* d_U9      = (const float*)d_in[1];
    const float* d_U10     = (const float*)d_in[2];
    const float* d_a       = (const float*)d_in[3];
    const float* d_adj9    = (const float*)d_in[4];
    const float* d_adj10   = (const float*)d_in[5];
    float*       d_o       = (float*)d_out;

    gat_fused_kernel<<<ROWBLOCKS, 256, 0, stream>>>(
        d_version, d_U9, d_U10, d_a, d_adj9, d_adj10, d_o);
}

// Round 5
// 45.718 us; speedup vs baseline: 1.1162x; 1.1162x over previous
//
#include <hip/hip_runtime.h>
#include <math.h>

#define N9     6000
#define N10    9000
#define FDIM   128
#define ALPHA  0.2f
#define MAXNBR 64
#define WPB    4                      // waves per 256-thread block
#define GRID   ((N10 + WPB - 1) / WPB) // 2250 blocks -> 9000 waves, covers both versions

typedef float f32x4 __attribute__((ext_vector_type(4)));

// Butterfly sum: every lane ends up holding the wave-wide total.
__device__ __forceinline__ float wave_bcast_sum(float x) {
    #pragma unroll
    for (int o = 32; o > 0; o >>= 1) x += __shfl_xor(x, o);
    return x;
}

// ---------------------------------------------------------------------------
// Wave-per-row fused GAT. Each 64-lane wave owns one query row end-to-end:
//   S0: load Q[i] (2 floats/lane), qa1/qa2 via butterfly reduce (all lanes).
//   S1: scan the 36KB adjacency row, 4-deep unrolled f32x4; push nonzero
//       column indices into this wave's LDS list (wave-local atomicAdd).
//   S2: per neighbor c: gather K[j_c] (coalesced), ka2 dot via butterfly,
//       e_c = leaky_relu(qa1 + ka2) -> LDS.
//   S3: 5-entry stable softmax, computed redundantly on all lanes (self is
//       always unmasked -> denom > 0, reference NaN path is dead).
//   S4: h = w_self*Q[i] + sum_c w_c*K[j_c] (K re-read, L1/L2-hot), elu, store.
// No __syncthreads in the row loop; intra-wave LDS visibility via
// __threadfence_block() (lockstep wave + in-order LDS pipe).
// ---------------------------------------------------------------------------
__global__ __launch_bounds__(256)
void gat_wave_kernel(const int* __restrict__ version,
                     const float* __restrict__ U9,
                     const float* __restrict__ U10,
                     const float* __restrict__ a,
                     const float* __restrict__ adj9to10,
                     const float* __restrict__ adj10to9,
                     float* __restrict__ out) {
    const int v  = version[0];
    const int nq = v ? N10 : N9;
    const int nk = v ? N9  : N10;
    const float* __restrict__ Q      = v ? U10 : U9;
    const float* __restrict__ K      = v ? U9  : U10;
    const float* __restrict__ adjmat = v ? adj10to9 : adj9to10;

    __shared__ float s_a1[FDIM], s_a2[FDIM];
    __shared__ int   s_j[WPB][MAXNBR];
    __shared__ float s_e[WPB][MAXNBR];
    __shared__ int   s_cnt[WPB];

    const int t    = threadIdx.x;
    const int wave = t >> 6;
    const int lane = t & 63;

    if (t < FDIM) { s_a1[t] = a[t]; s_a2[t] = a[FDIM + t]; }
    __syncthreads();  // once, outside the row loop

    const float a1lo = s_a1[lane], a1hi = s_a1[lane + 64];
    const float a2lo = s_a2[lane], a2hi = s_a2[lane + 64];

    const int gw = blockIdx.x * WPB + wave;
    const int nw = gridDim.x * WPB;
    const int n4 = nk >> 2;

    for (int i = gw; i < nq; i += nw) {
        if (lane == 0) s_cnt[wave] = 0;  // wave-local; ordered before atomics

        // S0: query row + dots
        const float* qr = Q + (size_t)i * FDIM;
        float qx0 = qr[lane], qx1 = qr[lane + 64];
        float qa1 = wave_bcast_sum(qx0 * a1lo + qx1 * a1hi);
        float qa2 = wave_bcast_sum(qx0 * a2lo + qx1 * a2hi);

        // S1: adjacency scan, 4 loads in flight per lane
        const f32x4* __restrict__ adj4 = (const f32x4*)(adjmat + (size_t)i * nk);
        int mycnt = 0;
        for (int p0 = lane; p0 < n4; p0 += 64 * 4) {
            const int p1 = p0 + 64, p2 = p0 + 128, p3 = p0 + 192;
            f32x4 r0 = adj4[p0];
            f32x4 r1 = (f32x4)(0.f), r2 = (f32x4)(0.f), r3 = (f32x4)(0.f);
            if (p1 < n4) r1 = adj4[p1];
            if (p2 < n4) r2 = adj4[p2];
            if (p3 < n4) r3 = adj4[p3];

            f32x4 rr[4] = {r0, r1, r2, r3};
            int   pp[4] = {p0, p1, p2, p3};
            #pragma unroll
            for (int u = 0; u < 4; ++u) {
                f32x4 vv = rr[u];
                if (vv.x > 0.f || vv.y > 0.f || vv.z > 0.f || vv.w > 0.f) {
                    float va[4] = {vv.x, vv.y, vv.z, vv.w};
                    #pragma unroll
                    for (int c = 0; c < 4; ++c) {
                        if (va[c] > 0.f) {
                            int idx = atomicAdd(&s_cnt[wave], 1);
                            if (idx < MAXNBR) s_j[wave][idx] = pp[u] * 4 + c;
                            ++mycnt;
                        }
                    }
                }
            }
        }
        // neighbor count via register butterfly (no LDS read needed)
        int cnt = mycnt;
        #pragma unroll
        for (int o = 32; o > 0; o >>= 1) cnt += __shfl_xor(cnt, o);
        if (cnt > MAXNBR) cnt = MAXNBR;
        __threadfence_block();  // s_j visible wave-wide

        // S2: e_c = leaky_relu(qa1 + K[j_c].a2)
        for (int c = 0; c < cnt; ++c) {
            const int j = s_j[wave][c];           // broadcast read
            const float* kr = K + (size_t)j * FDIM;
            float d = wave_bcast_sum(kr[lane] * a2lo + kr[lane + 64] * a2hi);
            float e = qa1 + d;
            if (lane == 0) s_e[wave][c] = (e >= 0.f) ? e : ALPHA * e;
        }
        __threadfence_block();  // s_e visible wave-wide

        // S3: stable softmax, redundant on all lanes (cnt ~ 4)
        float se = qa1 + qa2;
        se = (se >= 0.f) ? se : ALPHA * se;
        float m = se;
        for (int c = 0; c < cnt; ++c) m = fmaxf(m, s_e[wave][c]);
        float wself = __expf(se - m);
        float wsum  = wself;
        for (int c = 0; c < cnt; ++c) wsum += __expf(s_e[wave][c] - m);
        const float inv = 1.f / wsum;

        // S4: accumulate + elu + store (K rows L1/L2-hot from S2)
        float h0 = wself * inv * qx0;
        float h1 = wself * inv * qx1;
        for (int c = 0; c < cnt; ++c) {
            const int j = s_j[wave][c];
            const float w = __expf(s_e[wave][c] - m) * inv;
            const float* kr = K + (size_t)j * FDIM;
            h0 += w * kr[lane];
            h1 += w * kr[lane + 64];
        }
        h0 = (h0 > 0.f) ? h0 : expm1f(h0);
        h1 = (h1 > 0.f) ? h1 : expm1f(h1);
        out[(size_t)i * FDIM + lane]      = h0;
        out[(size_t)i * FDIM + lane + 64] = h1;
    }
}

extern "C" void kernel_launch(void* const* d_in, const int* in_sizes, int n_in,
                              void* d_out, int out_size, void* d_ws, size_t ws_size,
                              hipStream_t stream) {
    const int*   d_version = (const int*)d_in[0];
    const float* d_U9      = (const float*)d_in[1];
    const float* d_U10     = (const float*)d_in[2];
    const float* d_a       = (const float*)d_in[3];
    const float* d_adj9    = (const float*)d_in[4];
    const float* d_adj10   = (const float*)d_in[5];
    float*       d_o       = (float*)d_out;

    gat_wave_kernel<<<GRID, 256, 0, stream>>>(
        d_version, d_U9, d_U10, d_a, d_adj9, d_adj10, d_o);
}

// Round 6
// 44.908 us; speedup vs baseline: 1.1364x; 1.0180x over previous
//
#include <hip/hip_runtime.h>
#include <math.h>

#define N9     6000
#define N10    9000
#define FDIM   128
#define ALPHA  0.2f
#define MAXNBR 64
#define MAXREG 8                       // fast-path register-resident neighbors
#define WPB    4                       // waves per 256-thread block
#define GRID   ((N10 + WPB - 1) / WPB) // 2250 blocks -> 9000 waves, covers both versions

typedef float f32x4 __attribute__((ext_vector_type(4)));

// Butterfly sum: every lane ends up holding the wave-wide total.
__device__ __forceinline__ float wave_bcast_sum(float x) {
    #pragma unroll
    for (int o = 32; o > 0; o >>= 1) x += __shfl_xor(x, o);
    return x;
}

// ---------------------------------------------------------------------------
// Wave-per-row fused GAT. Each 64-lane wave owns one query row end-to-end:
//   S0: load Q[i] (2 floats/lane), qa1/qa2 via butterfly reduce.
//   S1: scan the adjacency row (f32x4, 4-deep); push nonzero column indices
//       into this wave's LDS list.
//   S2 fast (cnt<=8): predicated full-unroll batch-load of ALL neighbor rows
//       into static register arrays (one latency wait), ILP'd dot reduces,
//       in-register softmax, accumulate from the SAME registers (K read once).
//   S2 slow (cnt>8, rare): original serial per-neighbor path via LDS.
// No __syncthreads in the row loop; intra-wave LDS visibility via
// __threadfence_block().
// ---------------------------------------------------------------------------
__global__ __launch_bounds__(256)
void gat_wave_kernel(const int* __restrict__ version,
                     const float* __restrict__ U9,
                     const float* __restrict__ U10,
                     const float* __restrict__ a,
                     const float* __restrict__ adj9to10,
                     const float* __restrict__ adj10to9,
                     float* __restrict__ out) {
    const int v  = version[0];
    const int nq = v ? N10 : N9;
    const int nk = v ? N9  : N10;
    const float* __restrict__ Q      = v ? U10 : U9;
    const float* __restrict__ K      = v ? U9  : U10;
    const float* __restrict__ adjmat = v ? adj10to9 : adj9to10;

    __shared__ float s_a1[FDIM], s_a2[FDIM];
    __shared__ int   s_j[WPB][MAXNBR];
    __shared__ float s_e[WPB][MAXNBR];
    __shared__ int   s_cnt[WPB];

    const int t    = threadIdx.x;
    const int wave = t >> 6;
    const int lane = t & 63;

    if (t < FDIM) { s_a1[t] = a[t]; s_a2[t] = a[FDIM + t]; }
    __syncthreads();  // once, outside the row loop

    const float a1lo = s_a1[lane], a1hi = s_a1[lane + 64];
    const float a2lo = s_a2[lane], a2hi = s_a2[lane + 64];

    const int gw = blockIdx.x * WPB + wave;
    const int nw = gridDim.x * WPB;
    const int n4 = nk >> 2;

    for (int i = gw; i < nq; i += nw) {
        if (lane == 0) s_cnt[wave] = 0;  // wave-local; ordered before atomics

        // S0: query row + dots
        const float* qr = Q + (size_t)i * FDIM;
        float qx0 = qr[lane], qx1 = qr[lane + 64];
        float qa1 = wave_bcast_sum(qx0 * a1lo + qx1 * a1hi);
        float qa2 = wave_bcast_sum(qx0 * a2lo + qx1 * a2hi);

        // S1: adjacency scan, 4 loads in flight per lane
        const f32x4* __restrict__ adj4 = (const f32x4*)(adjmat + (size_t)i * nk);
        for (int p0 = lane; p0 < n4; p0 += 64 * 4) {
            const int p1 = p0 + 64, p2 = p0 + 128, p3 = p0 + 192;
            f32x4 r0 = adj4[p0];
            f32x4 r1 = (f32x4)(0.f), r2 = (f32x4)(0.f), r3 = (f32x4)(0.f);
            if (p1 < n4) r1 = adj4[p1];
            if (p2 < n4) r2 = adj4[p2];
            if (p3 < n4) r3 = adj4[p3];

            f32x4 rr[4] = {r0, r1, r2, r3};
            int   pp[4] = {p0, p1, p2, p3};
            #pragma unroll
            for (int u = 0; u < 4; ++u) {
                f32x4 vv = rr[u];
                if (vv.x > 0.f || vv.y > 0.f || vv.z > 0.f || vv.w > 0.f) {
                    float va[4] = {vv.x, vv.y, vv.z, vv.w};
                    #pragma unroll
                    for (int c = 0; c < 4; ++c) {
                        if (va[c] > 0.f) {
                            int idx = atomicAdd(&s_cnt[wave], 1);
                            if (idx < MAXNBR) s_j[wave][idx] = pp[u] * 4 + c;
                        }
                    }
                }
            }
        }
        __threadfence_block();  // s_j/s_cnt visible wave-wide
        int cnt = s_cnt[wave];
        if (cnt > MAXNBR) cnt = MAXNBR;

        // self score (needed by both paths)
        float se = qa1 + qa2;
        se = (se >= 0.f) ? se : ALPHA * se;

        float h0, h1;
        if (cnt <= MAXREG) {
            // ---- fast path: everything register-resident ----
            float k0[MAXREG], k1[MAXREG];
            #pragma unroll
            for (int c = 0; c < MAXREG; ++c) {
                if (c < cnt) {
                    const float* kr = K + (size_t)s_j[wave][c] * FDIM;
                    k0[c] = kr[lane]; k1[c] = kr[lane + 64];  // all issued before use
                }
            }
            float e[MAXREG];
            float m = se;
            #pragma unroll
            for (int c = 0; c < MAXREG; ++c) {
                if (c < cnt) {
                    float d  = wave_bcast_sum(k0[c] * a2lo + k1[c] * a2hi);
                    float ee = qa1 + d;
                    ee = (ee >= 0.f) ? ee : ALPHA * ee;
                    e[c] = ee;
                    m = fmaxf(m, ee);
                }
            }
            float wself = __expf(se - m);
            float wsum  = wself;
            float w[MAXREG];
            #pragma unroll
            for (int c = 0; c < MAXREG; ++c) {
                if (c < cnt) { w[c] = __expf(e[c] - m); wsum += w[c]; }
            }
            const float inv = 1.f / wsum;
            h0 = wself * inv * qx0;
            h1 = wself * inv * qx1;
            #pragma unroll
            for (int c = 0; c < MAXREG; ++c) {
                if (c < cnt) {
                    const float wc = w[c] * inv;
                    h0 += wc * k0[c];
                    h1 += wc * k1[c];
                }
            }
        } else {
            // ---- slow path (rare): serial per-neighbor via LDS ----
            for (int c = 0; c < cnt; ++c) {
                const int j = s_j[wave][c];
                const float* kr = K + (size_t)j * FDIM;
                float d = wave_bcast_sum(kr[lane] * a2lo + kr[lane + 64] * a2hi);
                float ee = qa1 + d;
                if (lane == 0) s_e[wave][c] = (ee >= 0.f) ? ee : ALPHA * ee;
            }
            __threadfence_block();
            float m = se;
            for (int c = 0; c < cnt; ++c) m = fmaxf(m, s_e[wave][c]);
            float wself = __expf(se - m);
            float wsum  = wself;
            for (int c = 0; c < cnt; ++c) wsum += __expf(s_e[wave][c] - m);
            const float inv = 1.f / wsum;
            h0 = wself * inv * qx0;
            h1 = wself * inv * qx1;
            for (int c = 0; c < cnt; ++c) {
                const int j = s_j[wave][c];
                const float wc = __expf(s_e[wave][c] - m) * inv;
                const float* kr = K + (size_t)j * FDIM;
                h0 += wc * kr[lane];
                h1 += wc * kr[lane + 64];
            }
        }

        h0 = (h0 > 0.f) ? h0 : expm1f(h0);
        h1 = (h1 > 0.f) ? h1 : expm1f(h1);
        out[(size_t)i * FDIM + lane]      = h0;
        out[(size_t)i * FDIM + lane + 64] = h1;
    }
}

extern "C" void kernel_launch(void* const* d_in, const int* in_sizes, int n_in,
                              void* d_out, int out_size, void* d_ws, size_t ws_size,
                              hipStream_t stream) {
    const int*   d_version = (const int*)d_in[0];
    const float* d_U9      = (const float*)d_in[1];
    const float* d_U10     = (const float*)d_in[2];
    const float* d_a       = (const float*)d_in[3];
    const float* d_adj9    = (const float*)d_in[4];
    const float* d_adj10   = (const float*)d_in[5];
    float*       d_o       = (float*)d_out;

    gat_wave_kernel<<<GRID, 256, 0, stream>>>(
        d_version, d_U9, d_U10, d_a, d_adj9, d_adj10, d_o);
}